// Round 9
// baseline (654.324 us; speedup 1.0000x reference)
//
#include <hip/hip_runtime.h>
#include <hip/hip_bf16.h>
#include <hip/hip_fp16.h>

#define N_NODES 50000
#define N_EDGES 800000
#define E_TOT   850000   // + self loops
#define SCAN_BLOCKS 196  // ceil(50000/256)
#define GBLK 64          // nodes per gemm block
#define GEMM_BLOCKS 782  // ceil(50000/64)
#define NRANGE 8
#define RANGE_SIZE 6250  // 50000/8
#define BIN_CAP 131072   // per-(xcd,range) segment capacity (worst case ~107K)

__device__ __forceinline__ int get_xcd() {
    int x;
    asm("s_getreg_b32 %0, hwreg(HW_REG_XCC_ID)" : "=s"(x));
    return x & 7;
}

// ---------------- phase 1: histogram + XCD-binned edge staging ----------------
// Reads ei once. For each edge: atomicAdd(counts[dst]) (hist) and append packed
// (dstLocal<<17 | src) to the dense segment gbin[(xcd*8+range)] — each segment
// is written by exactly one XCD -> full write-combining in that XCD's L2.
// Per-wave ballot waterfall: one cursor atomic per (wave, range) instead of per lane.
__global__ __launch_bounds__(256) void bin_kernel(const int* __restrict__ ei,
                                                  int* __restrict__ counts,
                                                  int* __restrict__ cursor,
                                                  unsigned* __restrict__ gbin) {
    const int lane = threadIdx.x & 63;
    const int xcd8 = get_xcd() * NRANGE;
    int e = (blockIdx.x * blockDim.x + threadIdx.x) * 4;

    int src[4], dst[4];
    bool valid = (e < E_TOT);
    if (valid) {
        if (e < N_EDGES) {
            int4 sv = *(const int4*)(ei + e);
            int4 dv = *(const int4*)(ei + N_EDGES + e);
            src[0] = sv.x; src[1] = sv.y; src[2] = sv.z; src[3] = sv.w;
            dst[0] = dv.x; dst[1] = dv.y; dst[2] = dv.z; dst[3] = dv.w;
        } else {
            int b = e - N_EDGES;
#pragma unroll
            for (int k = 0; k < 4; k++) { src[k] = b + k; dst[k] = b + k; }
        }
    }

#pragma unroll
    for (int k = 0; k < 4; k++) {
        int r = 8;  // invalid sentinel
        if (valid) {
            atomicAdd(&counts[dst[k]], 1);
            r = dst[k] / RANGE_SIZE;
        }
        // waterfall over the 8 ranges: leader lane does one cursor atomic
#pragma unroll
        for (int rr = 0; rr < NRANGE; rr++) {
            unsigned long long m = __ballot(r == rr);
            if (m == 0) continue;                       // wave-uniform
            if (r == rr) {
                int leader = __ffsll((unsigned long long)m) - 1;
                int rank = __popcll(m & ((1ULL << lane) - 1ULL));
                int b = 0;
                if (rank == 0) b = atomicAdd(&cursor[xcd8 + rr], __popcll(m));
                b = __shfl(b, leader, 64);
                unsigned entry = ((unsigned)(dst[k] - rr * RANGE_SIZE) << 17) |
                                 (unsigned)src[k];
                gbin[(size_t)(xcd8 + rr) * BIN_CAP + b + rank] = entry;
            }
        }
    }
}

// ---------------- scans (unchanged) ----------------

__global__ __launch_bounds__(256) void scan1_kernel(const int* __restrict__ counts,
                                                    int* __restrict__ localScan,
                                                    int* __restrict__ blockSums) {
    __shared__ int tmp[256];
    int t = threadIdx.x, i = blockIdx.x * 256 + t;
    int v = (i < N_NODES) ? counts[i] : 0;
    tmp[t] = v;
    __syncthreads();
    for (int d = 1; d < 256; d <<= 1) {
        int u = (t >= d) ? tmp[t - d] : 0;
        __syncthreads();
        tmp[t] += u;
        __syncthreads();
    }
    if (i < N_NODES) localScan[i] = tmp[t] - v;
    if (t == 255) blockSums[blockIdx.x] = tmp[t];
}

__global__ __launch_bounds__(256) void scan23_kernel(const int* __restrict__ localScan,
                                                     const int* __restrict__ blockSums,
                                                     int* __restrict__ offs,
                                                     int* __restrict__ fill) {
    __shared__ int tmp[256];
    int t = threadIdx.x;
    int v = (t < SCAN_BLOCKS) ? blockSums[t] : 0;
    tmp[t] = v;
    __syncthreads();
    for (int d = 1; d < 256; d <<= 1) {
        int u = (t >= d) ? tmp[t - d] : 0;
        __syncthreads();
        tmp[t] += u;
        __syncthreads();
    }
    int b = blockIdx.x;
    int base = (b == 0) ? 0 : tmp[b - 1];
    int i = b * 256 + t;
    if (i < N_NODES) {
        int o = localScan[i] + base;
        offs[i] = o;
        fill[i] = o;
    }
    if (i == 0) offs[N_NODES] = E_TOT;
}

// ---------------- phase 2: range-local scatter from dense segments ----------------
// blockIdx&7 = range -> all blocks of a range land on one XCD; its 425 KB bucket
// region + 25 KB fill slice stay L2-resident with no streaming pollution.
__global__ __launch_bounds__(512) void scat2_kernel(const int* __restrict__ cursor,
                                                    const unsigned* __restrict__ gbin,
                                                    int* __restrict__ fill,
                                                    int* __restrict__ bucket) {
    int r = blockIdx.x & (NRANGE - 1);
    int g = blockIdx.x >> 3;   // 0..31
    for (int x = 0; x < 8; x++) {
        int n = cursor[x * NRANGE + r];
        const unsigned* seg = gbin + (size_t)(x * NRANGE + r) * BIN_CAP;
        for (int i = g * 512 + threadIdx.x; i < n; i += 32 * 512) {
            unsigned en = seg[i];
            int dst = r * RANGE_SIZE + (int)(en >> 17);
            int s = (int)(en & 0x1FFFFu);
            int p = atomicAdd(&fill[dst], 1);
            bucket[p] = s;
        }
    }
}

// ---------------- layer 1 GEMM (R8-proven): wave-uniform W via scalar cache ----
__global__ __launch_bounds__(512) void gemm1_kernel(const float* __restrict__ x,
                                                    const float* __restrict__ W1,
                                                    const float* __restrict__ asrc1,
                                                    const float* __restrict__ adst1,
                                                    __half* __restrict__ h1,
                                                    float* __restrict__ as1,
                                                    float* __restrict__ ad1) {
    __shared__ float xs[32 * 65];
    __shared__ float sredA[8 * 64];
    __shared__ float sredB[8 * 64];

    const int tid  = threadIdx.x;
    const int lane = tid & 63;
    const int w    = tid >> 6;
    const int head = __builtin_amdgcn_readfirstlane(w >> 1);
    const int ch   = __builtin_amdgcn_readfirstlane(w & 1);
    const int base = blockIdx.x * GBLK;
    const int node = base + lane;

    const float* __restrict__ wh = W1 + head * 32 + ch * 16;

    float acc[16];
#pragma unroll
    for (int j = 0; j < 16; j++) acc[j] = 0.f;

    for (int kt = 0; kt < 4; kt++) {
        __syncthreads();
        {
            int row = tid >> 3, c4 = tid & 7;
            int n2 = base + row;
            float4 v = make_float4(0.f, 0.f, 0.f, 0.f);
            if (n2 < N_NODES)
                v = *(const float4*)(x + (size_t)n2 * 128 + kt * 32 + c4 * 4);
            xs[(c4 * 4 + 0) * 65 + row] = v.x;
            xs[(c4 * 4 + 1) * 65 + row] = v.y;
            xs[(c4 * 4 + 2) * 65 + row] = v.z;
            xs[(c4 * 4 + 3) * 65 + row] = v.w;
        }
        __syncthreads();

#pragma unroll 4
        for (int kk = 0; kk < 32; kk++) {
            float xv = xs[kk * 65 + lane];
            const float* __restrict__ wr = wh + (size_t)(kt * 32 + kk) * 128;
#pragma unroll
            for (int j = 0; j < 16; j++)
                acc[j] += xv * wr[j];
        }
    }

    if (node < N_NODES) {
        __half2 hp[8];
#pragma unroll
        for (int j = 0; j < 8; j++)
            hp[j] = __floats2half2_rn(acc[2 * j], acc[2 * j + 1]);
        float4* dst = (float4*)(h1 + (size_t)node * 128 + head * 32 + ch * 16);
        dst[0] = ((float4*)hp)[0];
        dst[1] = ((float4*)hp)[1];
    }

    float sa = 0.f, da = 0.f;
#pragma unroll
    for (int j = 0; j < 16; j++) {
        float v = acc[j];
        sa += v * asrc1[head * 32 + ch * 16 + j];
        da += v * adst1[head * 32 + ch * 16 + j];
    }
    sredA[w * 64 + lane] = sa;
    sredB[w * 64 + lane] = da;
    __syncthreads();
    if (tid < 256) {
        int hh = tid >> 6;
        int nd = base + lane;
        if (nd < N_NODES) {
            as1[nd * 4 + hh] = sredA[(hh * 2) * 64 + lane] + sredA[(hh * 2 + 1) * 64 + lane];
            ad1[nd * 4 + hh] = sredB[(hh * 2) * 64 + lane] + sredB[(hh * 2 + 1) * 64 + lane];
        }
    }
}

// ---------------- layer 1 aggregation with FUSED per-node sort ----------------
// wave per node. First: bitonic-sort the <=64 srcs in-register (deterministic
// order), park in a 64-int LDS wave buffer. Then the R8 gather layout:
// lane = (edge-subset l>>4, channel-group l&15 -> 8 channels).
__global__ __launch_bounds__(256) void agg1_kernel(const __half* __restrict__ h1,
                                                   const float* __restrict__ as1,
                                                   const float* __restrict__ ad1,
                                                   const int* __restrict__ offs,
                                                   int* __restrict__ bucket,
                                                   const float* __restrict__ b1,
                                                   const float* __restrict__ W2,
                                                   float* __restrict__ h2s) {
    __shared__ int lbuf[4][64];
    int w = threadIdx.x >> 6, l = threadIdx.x & 63;
    int node = blockIdx.x * 4 + w;
    if (node >= N_NODES) return;
    int sub = l & 15;
    int ep  = l >> 4;
    int head = sub >> 2;
    float adh = ad1[node * 4 + head];
    int a = offs[node];
    int deg = offs[node + 1] - a;

    bool small = (deg <= 64);
    if (small) {
        int v = (l < deg) ? bucket[a + l] : 0x7fffffff;
#pragma unroll
        for (int k = 2; k <= 64; k <<= 1) {
#pragma unroll
            for (int j = k >> 1; j >= 1; j >>= 1) {
                int u = __shfl_xor(v, j, 64);
                bool up    = ((l & k) == 0);
                bool lower = ((l & j) == 0);
                int mn = min(v, u), mx = max(v, u);
                v = (up == lower) ? mn : mx;
            }
        }
        lbuf[w][l] = v;
    } else if (l == 0) {
        // fallback (deg>64: essentially impossible here, kept for correctness)
        for (int i = a + 1; i < a + deg; i++) {
            int key = bucket[i];
            int j = i - 1;
            while (j >= a && bucket[j] > key) { bucket[j + 1] = bucket[j]; j--; }
            bucket[j + 1] = key;
        }
    }

    float c[8];
#pragma unroll
    for (int k = 0; k < 8; k++) c[k] = 0.f;
    float sx = 0.f;

    auto body = [&](int s, float ex) {
        float4 hv = *(const float4*)(h1 + (size_t)s * 128 + sub * 8);
        const __half2* hh = (const __half2*)&hv;
        float2 f0 = __half22float2(hh[0]);
        float2 f1 = __half22float2(hh[1]);
        float2 f2 = __half22float2(hh[2]);
        float2 f3 = __half22float2(hh[3]);
        sx += ex;
        c[0] += ex * f0.x; c[1] += ex * f0.y;
        c[2] += ex * f1.x; c[3] += ex * f1.y;
        c[4] += ex * f2.x; c[5] += ex * f2.y;
        c[6] += ex * f3.x; c[7] += ex * f3.y;
    };

    if (small) {
        for (int i = 0; i < deg; i += 4) {
            int idx = i + ep;
            bool valid = idx < deg;
            int s = lbuf[w][valid ? idx : 0];
            float e = as1[s * 4 + head] + adh;
            e = fmaxf(e, 0.2f * e);
            float ex = valid ? __expf(e) : 0.f;
            body(s, ex);
        }
    } else {
        for (int i = 0; i < deg; i += 4) {
            int idx = i + ep;
            bool valid = idx < deg;
            int s = bucket[a + (valid ? idx : 0)];
            float e = as1[s * 4 + head] + adh;
            e = fmaxf(e, 0.2f * e);
            float ex = valid ? __expf(e) : 0.f;
            body(s, ex);
        }
    }

#pragma unroll
    for (int k = 0; k < 8; k++) {
        c[k] += __shfl_xor(c[k], 16, 64);
        c[k] += __shfl_xor(c[k], 32, 64);
    }
    sx += __shfl_xor(sx, 16, 64);
    sx += __shfl_xor(sx, 32, 64);

    float r = 1.f / (sx + 1e-16f);
    float4 blo = ((const float4*)b1)[sub * 2];
    float4 bhi = ((const float4*)b1)[sub * 2 + 1];
    float4 wlo = ((const float4*)W2)[sub * 2];
    float4 whi = ((const float4*)W2)[sub * 2 + 1];
    float ob[8] = {blo.x, blo.y, blo.z, blo.w, bhi.x, bhi.y, bhi.z, bhi.w};
    float ow[8] = {wlo.x, wlo.y, wlo.z, wlo.w, whi.x, whi.y, whi.z, whi.w};
    float p = 0.f;
#pragma unroll
    for (int k = 0; k < 8; k++) {
        float o = c[k] * r + ob[k];
        float el = (o > 0.f) ? o : (__expf(o) - 1.f);
        p += el * ow[k];
    }
    p += __shfl_xor(p, 1, 64);
    p += __shfl_xor(p, 2, 64);
    p += __shfl_xor(p, 4, 64);
    p += __shfl_xor(p, 8, 64);
    if (l == 0) h2s[node] = p;
}

// ---------------- layer 2 aggregation ----------------
__global__ __launch_bounds__(256) void agg2_kernel(const float* __restrict__ h2s,
                                                   const int* __restrict__ offs,
                                                   const int* __restrict__ bucket,
                                                   const float* __restrict__ asrc2,
                                                   const float* __restrict__ adst2,
                                                   const float* __restrict__ b2,
                                                   float* __restrict__ out) {
    int w = threadIdx.x >> 6, l = threadIdx.x & 63;
    int node = blockIdx.x * 4 + w;
    if (node >= N_NODES) return;
    float asc = asrc2[0], adc = adst2[0], bias = b2[0];
    float adn = h2s[node] * adc;
    int a = offs[node], b = offs[node + 1];
    float sx = 0.f, sw = 0.f;
    for (int i = a + l; i < b; i += 64) {
        float hs = h2s[bucket[i]];
        float e = hs * asc + adn;
        e = fmaxf(e, 0.2f * e);
        float ex = __expf(e);
        sx += ex;
        sw += ex * hs;
    }
#pragma unroll
    for (int o = 32; o > 0; o >>= 1) {
        sx += __shfl_xor(sx, o, 64);
        sw += __shfl_xor(sw, o, 64);
    }
    if (l == 0) out[node] = sw / (sx + 1e-16f) + bias;
}

// ---------------- launch ----------------

extern "C" void kernel_launch(void* const* d_in, const int* in_sizes, int n_in,
                              void* d_out, int out_size, void* d_ws, size_t ws_size,
                              hipStream_t stream) {
    const float* x     = (const float*)d_in[0];
    const int*   ei    = (const int*)d_in[1];
    const float* W1    = (const float*)d_in[2];
    const float* asrc1 = (const float*)d_in[3];
    const float* adst1 = (const float*)d_in[4];
    const float* b1    = (const float*)d_in[5];
    const float* W2    = (const float*)d_in[6];
    const float* asrc2 = (const float*)d_in[7];
    const float* adst2 = (const float*)d_in[8];
    const float* b2    = (const float*)d_in[9];
    float* out = (float*)d_out;

    char* ws = (char*)d_ws;
    size_t o = 0;
    auto alloc = [&](size_t bytes) -> void* {
        void* p = ws + o;
        o += (bytes + 255) & ~(size_t)255;
        return p;
    };
    int* counts  = (int*)alloc((size_t)N_NODES * 4);
    int* offs    = (int*)alloc((size_t)(N_NODES + 1) * 4);
    int* fill    = (int*)alloc((size_t)N_NODES * 4);
    int* bucket  = (int*)alloc((size_t)E_TOT * 4);
    __half* h1   = (__half*)alloc((size_t)N_NODES * 128 * 2);
    float* as1   = (float*)alloc((size_t)N_NODES * 4 * 4);
    float* ad1   = (float*)alloc((size_t)N_NODES * 4 * 4);
    float* h2s   = (float*)alloc((size_t)N_NODES * 4);
    int* localScan = (int*)alloc((size_t)N_NODES * 4);
    int* blockSums = (int*)alloc((size_t)SCAN_BLOCKS * 4);
    int* cursor    = (int*)alloc((size_t)64 * 4);
    unsigned* gbin = (unsigned*)alloc((size_t)64 * BIN_CAP * 4);

    hipMemsetAsync(counts, 0, (size_t)N_NODES * 4, stream);
    hipMemsetAsync(cursor, 0, 64 * 4, stream);

    bin_kernel<<<(E_TOT / 4 + 255) / 256, 256, 0, stream>>>(ei, counts, cursor, gbin);
    scan1_kernel<<<SCAN_BLOCKS, 256, 0, stream>>>(counts, localScan, blockSums);
    scan23_kernel<<<SCAN_BLOCKS, 256, 0, stream>>>(localScan, blockSums, offs, fill);
    scat2_kernel<<<32 * NRANGE, 512, 0, stream>>>(cursor, gbin, fill, bucket);

    gemm1_kernel<<<GEMM_BLOCKS, 512, 0, stream>>>(
        x, W1, asrc1, adst1, h1, as1, ad1);

    agg1_kernel<<<(N_NODES + 3) / 4, 256, 0, stream>>>(
        h1, as1, ad1, offs, bucket, b1, W2, h2s);

    agg2_kernel<<<(N_NODES + 3) / 4, 256, 0, stream>>>(
        h2s, offs, bucket, asrc2, adst2, b2, out);
}

// Round 10
// 168.856 us; speedup vs baseline: 3.8750x; 3.8750x over previous
//
#include <hip/hip_runtime.h>
#include <hip/hip_bf16.h>
#include <hip/hip_fp16.h>

#define N_NODES 50000
#define N_EDGES 800000
#define E_TOT   850000   // + self loops
#define SCAN_BLOCKS 196  // ceil(50000/256)
#define GBLK 64          // nodes per gemm block
#define GEMM_BLOCKS 782  // ceil(50000/64)
#define SCAT_BLOCKS 416  // ceil(850000/4/512)

// ---------------- CSR build ----------------

__global__ void hist_kernel(const int* __restrict__ ei, int* __restrict__ counts) {
    int e = (blockIdx.x * blockDim.x + threadIdx.x) * 4;
    if (e >= E_TOT) return;
    if (e < N_EDGES) {
        int4 dv = *(const int4*)(ei + N_EDGES + e);
        atomicAdd(&counts[dv.x], 1);
        atomicAdd(&counts[dv.y], 1);
        atomicAdd(&counts[dv.z], 1);
        atomicAdd(&counts[dv.w], 1);
    } else {
        int b = e - N_EDGES;
        atomicAdd(&counts[b + 0], 1);
        atomicAdd(&counts[b + 1], 1);
        atomicAdd(&counts[b + 2], 1);
        atomicAdd(&counts[b + 3], 1);
    }
}

__global__ __launch_bounds__(256) void scan1_kernel(const int* __restrict__ counts,
                                                    int* __restrict__ localScan,
                                                    int* __restrict__ blockSums) {
    __shared__ int tmp[256];
    int t = threadIdx.x, i = blockIdx.x * 256 + t;
    int v = (i < N_NODES) ? counts[i] : 0;
    tmp[t] = v;
    __syncthreads();
    for (int d = 1; d < 256; d <<= 1) {
        int u = (t >= d) ? tmp[t - d] : 0;
        __syncthreads();
        tmp[t] += u;
        __syncthreads();
    }
    if (i < N_NODES) localScan[i] = tmp[t] - v;  // exclusive
    if (t == 255) blockSums[blockIdx.x] = tmp[t];
}

// merged scan2+scan3: every block redundantly scans the 196 block sums (cheap),
// then writes its 256 offsets.
__global__ __launch_bounds__(256) void scan23_kernel(const int* __restrict__ localScan,
                                                     const int* __restrict__ blockSums,
                                                     int* __restrict__ offs,
                                                     int* __restrict__ fill) {
    __shared__ int tmp[256];
    int t = threadIdx.x;
    int v = (t < SCAN_BLOCKS) ? blockSums[t] : 0;
    tmp[t] = v;
    __syncthreads();
    for (int d = 1; d < 256; d <<= 1) {
        int u = (t >= d) ? tmp[t - d] : 0;
        __syncthreads();
        tmp[t] += u;
        __syncthreads();
    }
    int b = blockIdx.x;
    int base = (b == 0) ? 0 : tmp[b - 1];
    int i = b * 256 + t;
    if (i < N_NODES) {
        int o = localScan[i] + base;
        offs[i] = o;
        fill[i] = o;
    }
    if (i == 0) offs[N_NODES] = E_TOT;
}

// ---------------- fat kernel: scatter (blocks < SCAT_BLOCKS) || gemm1 (rest) ----
// scatter: 4 edges/thread, 4 independent atomic+store chains, ei read ONCE.
// gemm: block = 512 thr = 8 waves; wave w: head=w>>1, colhalf=w&1 (wave-uniform ->
// W reads are s_loads through the scalar cache). lane = node. R8-proven design.
__global__ __launch_bounds__(512) void fat_kernel(const float* __restrict__ x,
                                                  const float* __restrict__ W1,
                                                  const float* __restrict__ asrc1,
                                                  const float* __restrict__ adst1,
                                                  __half* __restrict__ h1,
                                                  float* __restrict__ as1,
                                                  float* __restrict__ ad1,
                                                  const int* __restrict__ ei,
                                                  int* __restrict__ fill,
                                                  int* __restrict__ bucket) {
    __shared__ float xs[32 * 65];
    __shared__ float sredA[8 * 64];
    __shared__ float sredB[8 * 64];

    if (blockIdx.x < SCAT_BLOCKS) {
        // ---- scatter part ----
        int e = (blockIdx.x * 512 + threadIdx.x) * 4;
        if (e >= E_TOT) return;
        int s0, s1, s2, s3, d0, d1, d2, d3;
        if (e < N_EDGES) {
            int4 sv = *(const int4*)(ei + e);
            int4 dv = *(const int4*)(ei + N_EDGES + e);
            s0 = sv.x; s1 = sv.y; s2 = sv.z; s3 = sv.w;
            d0 = dv.x; d1 = dv.y; d2 = dv.z; d3 = dv.w;
        } else {
            int b = e - N_EDGES;
            s0 = d0 = b; s1 = d1 = b + 1; s2 = d2 = b + 2; s3 = d3 = b + 3;
        }
        int p0 = atomicAdd(&fill[d0], 1);
        int p1 = atomicAdd(&fill[d1], 1);
        int p2 = atomicAdd(&fill[d2], 1);
        int p3 = atomicAdd(&fill[d3], 1);
        bucket[p0] = s0;
        bucket[p1] = s1;
        bucket[p2] = s2;
        bucket[p3] = s3;
        return;
    }

    // ---- gemm part ----
    const int tid  = threadIdx.x;
    const int lane = tid & 63;
    const int w    = tid >> 6;
    const int head = __builtin_amdgcn_readfirstlane(w >> 1);
    const int ch   = __builtin_amdgcn_readfirstlane(w & 1);
    const int base = (blockIdx.x - SCAT_BLOCKS) * GBLK;
    const int node = base + lane;

    const float* __restrict__ wh = W1 + head * 32 + ch * 16;

    float acc[16];
#pragma unroll
    for (int j = 0; j < 16; j++) acc[j] = 0.f;

    for (int kt = 0; kt < 4; kt++) {
        __syncthreads();
        {
            int row = tid >> 3, c4 = tid & 7;
            int n2 = base + row;
            float4 v = make_float4(0.f, 0.f, 0.f, 0.f);
            if (n2 < N_NODES)
                v = *(const float4*)(x + (size_t)n2 * 128 + kt * 32 + c4 * 4);
            xs[(c4 * 4 + 0) * 65 + row] = v.x;
            xs[(c4 * 4 + 1) * 65 + row] = v.y;
            xs[(c4 * 4 + 2) * 65 + row] = v.z;
            xs[(c4 * 4 + 3) * 65 + row] = v.w;
        }
        __syncthreads();

#pragma unroll 4
        for (int kk = 0; kk < 32; kk++) {
            float xv = xs[kk * 65 + lane];
            const float* __restrict__ wr = wh + (size_t)(kt * 32 + kk) * 128;
#pragma unroll
            for (int j = 0; j < 16; j++)
                acc[j] += xv * wr[j];
        }
    }

    if (node < N_NODES) {
        __half2 hp[8];
#pragma unroll
        for (int j = 0; j < 8; j++)
            hp[j] = __floats2half2_rn(acc[2 * j], acc[2 * j + 1]);
        float4* dst = (float4*)(h1 + (size_t)node * 128 + head * 32 + ch * 16);
        dst[0] = ((float4*)hp)[0];
        dst[1] = ((float4*)hp)[1];
    }

    float sa = 0.f, da = 0.f;
#pragma unroll
    for (int j = 0; j < 16; j++) {
        float v = acc[j];
        sa += v * asrc1[head * 32 + ch * 16 + j];
        da += v * adst1[head * 32 + ch * 16 + j];
    }
    sredA[w * 64 + lane] = sa;
    sredB[w * 64 + lane] = da;
    __syncthreads();
    if (tid < 256) {
        int hh = tid >> 6;
        int nd = base + lane;
        if (nd < N_NODES) {
            as1[nd * 4 + hh] = sredA[(hh * 2) * 64 + lane] + sredA[(hh * 2 + 1) * 64 + lane];
            ad1[nd * 4 + hh] = sredB[(hh * 2) * 64 + lane] + sredB[(hh * 2 + 1) * 64 + lane];
        }
    }
}

// ---------------- layer 1 aggregation (+bias, ELU, layer-2 projection) ----------------
// wave per node. lane = (edge-subset l>>4, channel-group l&15 -> 8 channels).
// One dwordx4 h1 load covers 4 src rows per iteration; exp/leaky amortize over
// 4 edges. Bucket is UNSORTED: aggregation is an order-independent multiset sum
// (fp reorder noise ~1e-6 << 8.6e-3 threshold).
__global__ __launch_bounds__(256) void agg1_kernel(const __half* __restrict__ h1,
                                                   const float* __restrict__ as1,
                                                   const float* __restrict__ ad1,
                                                   const int* __restrict__ offs,
                                                   const int* __restrict__ bucket,
                                                   const float* __restrict__ b1,
                                                   const float* __restrict__ W2,
                                                   float* __restrict__ h2s) {
    int w = threadIdx.x >> 6, l = threadIdx.x & 63;
    int node = blockIdx.x * 4 + w;
    if (node >= N_NODES) return;
    int sub = l & 15;            // channels 8*sub .. 8*sub+7
    int ep  = l >> 4;            // edge subset 0..3
    int head = sub >> 2;
    float adh = ad1[node * 4 + head];
    int a = offs[node];
    int deg = offs[node + 1] - a;

    float c[8];
#pragma unroll
    for (int k = 0; k < 8; k++) c[k] = 0.f;
    float sx = 0.f;

    for (int i = 0; i < deg; i += 4) {
        int idx = i + ep;
        bool valid = idx < deg;
        int s = bucket[a + (valid ? idx : 0)];
        float e = as1[s * 4 + head] + adh;
        e = fmaxf(e, 0.2f * e);                     // leaky_relu, slope<1
        float ex = valid ? __expf(e) : 0.f;
        float4 hv = *(const float4*)(h1 + (size_t)s * 128 + sub * 8);
        const __half2* hh = (const __half2*)&hv;
        float2 f0 = __half22float2(hh[0]);
        float2 f1 = __half22float2(hh[1]);
        float2 f2 = __half22float2(hh[2]);
        float2 f3 = __half22float2(hh[3]);
        sx += ex;
        c[0] += ex * f0.x; c[1] += ex * f0.y;
        c[2] += ex * f1.x; c[3] += ex * f1.y;
        c[4] += ex * f2.x; c[5] += ex * f2.y;
        c[6] += ex * f3.x; c[7] += ex * f3.y;
    }

    // reduce over edge subsets (lane bits 4,5)
#pragma unroll
    for (int k = 0; k < 8; k++) {
        c[k] += __shfl_xor(c[k], 16, 64);
        c[k] += __shfl_xor(c[k], 32, 64);
    }
    sx += __shfl_xor(sx, 16, 64);
    sx += __shfl_xor(sx, 32, 64);

    float r = 1.f / (sx + 1e-16f);
    float4 blo = ((const float4*)b1)[sub * 2];
    float4 bhi = ((const float4*)b1)[sub * 2 + 1];
    float4 wlo = ((const float4*)W2)[sub * 2];
    float4 whi = ((const float4*)W2)[sub * 2 + 1];
    float ob[8] = {blo.x, blo.y, blo.z, blo.w, bhi.x, bhi.y, bhi.z, bhi.w};
    float ow[8] = {wlo.x, wlo.y, wlo.z, wlo.w, whi.x, whi.y, whi.z, whi.w};
    float p = 0.f;
#pragma unroll
    for (int k = 0; k < 8; k++) {
        float o = c[k] * r + ob[k];
        float el = (o > 0.f) ? o : (__expf(o) - 1.f);  // ELU
        p += el * ow[k];
    }
    // reduce over channel groups (lane bits 0..3)
    p += __shfl_xor(p, 1, 64);
    p += __shfl_xor(p, 2, 64);
    p += __shfl_xor(p, 4, 64);
    p += __shfl_xor(p, 8, 64);
    if (l == 0) h2s[node] = p;
}

// ---------------- layer 2 aggregation ----------------
__global__ __launch_bounds__(256) void agg2_kernel(const float* __restrict__ h2s,
                                                   const int* __restrict__ offs,
                                                   const int* __restrict__ bucket,
                                                   const float* __restrict__ asrc2,
                                                   const float* __restrict__ adst2,
                                                   const float* __restrict__ b2,
                                                   float* __restrict__ out) {
    int w = threadIdx.x >> 6, l = threadIdx.x & 63;
    int node = blockIdx.x * 4 + w;
    if (node >= N_NODES) return;
    float asc = asrc2[0], adc = adst2[0], bias = b2[0];
    float adn = h2s[node] * adc;
    int a = offs[node], b = offs[node + 1];
    float sx = 0.f, sw = 0.f;
    for (int i = a + l; i < b; i += 64) {
        float hs = h2s[bucket[i]];
        float e = hs * asc + adn;
        e = fmaxf(e, 0.2f * e);
        float ex = __expf(e);
        sx += ex;
        sw += ex * hs;
    }
#pragma unroll
    for (int o = 32; o > 0; o >>= 1) {
        sx += __shfl_xor(sx, o, 64);
        sw += __shfl_xor(sw, o, 64);
    }
    if (l == 0) out[node] = sw / (sx + 1e-16f) + bias;
}

// ---------------- launch ----------------

extern "C" void kernel_launch(void* const* d_in, const int* in_sizes, int n_in,
                              void* d_out, int out_size, void* d_ws, size_t ws_size,
                              hipStream_t stream) {
    const float* x     = (const float*)d_in[0];
    const int*   ei    = (const int*)d_in[1];
    const float* W1    = (const float*)d_in[2];
    const float* asrc1 = (const float*)d_in[3];
    const float* adst1 = (const float*)d_in[4];
    const float* b1    = (const float*)d_in[5];
    const float* W2    = (const float*)d_in[6];
    const float* asrc2 = (const float*)d_in[7];
    const float* adst2 = (const float*)d_in[8];
    const float* b2    = (const float*)d_in[9];
    float* out = (float*)d_out;

    char* ws = (char*)d_ws;
    size_t o = 0;
    auto alloc = [&](size_t bytes) -> void* {
        void* p = ws + o;
        o += (bytes + 255) & ~(size_t)255;
        return p;
    };
    int* counts  = (int*)alloc((size_t)N_NODES * 4);
    int* offs    = (int*)alloc((size_t)(N_NODES + 1) * 4);
    int* fill    = (int*)alloc((size_t)N_NODES * 4);
    int* bucket  = (int*)alloc((size_t)E_TOT * 4);
    __half* h1   = (__half*)alloc((size_t)N_NODES * 128 * 2);
    float* as1   = (float*)alloc((size_t)N_NODES * 4 * 4);
    float* ad1   = (float*)alloc((size_t)N_NODES * 4 * 4);
    float* h2s   = (float*)alloc((size_t)N_NODES * 4);
    int* localScan = (int*)alloc((size_t)N_NODES * 4);
    int* blockSums = (int*)alloc((size_t)SCAN_BLOCKS * 4);

    hipMemsetAsync(counts, 0, (size_t)N_NODES * 4, stream);

    hist_kernel<<<(E_TOT / 4 + 255) / 256, 256, 0, stream>>>(ei, counts);
    scan1_kernel<<<SCAN_BLOCKS, 256, 0, stream>>>(counts, localScan, blockSums);
    scan23_kernel<<<SCAN_BLOCKS, 256, 0, stream>>>(localScan, blockSums, offs, fill);

    fat_kernel<<<SCAT_BLOCKS + GEMM_BLOCKS, 512, 0, stream>>>(
        x, W1, asrc1, adst1, h1, as1, ad1, ei, fill, bucket);

    agg1_kernel<<<(N_NODES + 3) / 4, 256, 0, stream>>>(
        h1, as1, ad1, offs, bucket, b1, W2, h2s);

    agg2_kernel<<<(N_NODES + 3) / 4, 256, 0, stream>>>(
        h2s, offs, bucket, asrc2, adst2, b2, out);
}

// Round 11
// 102.697 us; speedup vs baseline: 6.3714x; 1.6442x over previous
//
#include <hip/hip_runtime.h>
#include <hip/hip_bf16.h>
#include <hip/hip_fp16.h>

#define N_NODES 50000
#define N_EDGES 800000
#define E_TOT   850000   // + self loops (multiples of 8: chunks never straddle)
#define GBLK 64          // nodes per gemm block
#define GEMM_BLOCKS 782  // ceil(50000/64)
#define NR 196           // dst ranges of 256 nodes
#define EPB 4096         // edges per bin block
#define BIN_BLOCKS 208   // ceil(850000/4096)
#define SEGCAP 8192      // per-range segment capacity (avg 4337, sd ~66)

// =========== fat kernel: bin (blocks < BIN_BLOCKS) || gemm1 (rest) ===========
// bin: LDS-count 4096 edges into 196 dst-ranges, one global cursor atomic per
// (block,range) -> per-range segments receive ~21-entry DENSE runs (no random
// 4B scatter). Packed entry = (dstLocal<<17 | src), both fit (256, 2^17>50000).
// gemm: R8/R10-proven wave-uniform-W design (W via scalar cache), lane = node.
__global__ __launch_bounds__(512) void fat_kernel(const float* __restrict__ x,
                                                  const float* __restrict__ W1,
                                                  const float* __restrict__ asrc1,
                                                  const float* __restrict__ adst1,
                                                  __half* __restrict__ h1,
                                                  float* __restrict__ as1,
                                                  float* __restrict__ ad1,
                                                  const int* __restrict__ ei,
                                                  int* __restrict__ rangeCursor,
                                                  unsigned* __restrict__ gseg) {
    __shared__ float xs[32 * 65];
    __shared__ float sredA[8 * 64];
    __shared__ float sredB[8 * 64];
    __shared__ int cnt[NR];
    __shared__ int gbase[NR];

    const int tid = threadIdx.x;

    if (blockIdx.x < BIN_BLOCKS) {
        // ---- bin part ----
        for (int i = tid; i < NR; i += 512) cnt[i] = 0;
        __syncthreads();

        int e0 = blockIdx.x * EPB + tid * 8;
        bool valid = (e0 < E_TOT);           // chunk fully valid or fully not
        int src[8], dst[8], rg[8], rk[8];
        if (valid) {
            if (e0 < N_EDGES) {
                int4 a = *(const int4*)(ei + e0);
                int4 b = *(const int4*)(ei + e0 + 4);
                int4 c = *(const int4*)(ei + N_EDGES + e0);
                int4 d = *(const int4*)(ei + N_EDGES + e0 + 4);
                src[0]=a.x; src[1]=a.y; src[2]=a.z; src[3]=a.w;
                src[4]=b.x; src[5]=b.y; src[6]=b.z; src[7]=b.w;
                dst[0]=c.x; dst[1]=c.y; dst[2]=c.z; dst[3]=c.w;
                dst[4]=d.x; dst[5]=d.y; dst[6]=d.z; dst[7]=d.w;
            } else {
#pragma unroll
                for (int k = 0; k < 8; k++) { src[k] = dst[k] = e0 + k - N_EDGES; }
            }
#pragma unroll
            for (int k = 0; k < 8; k++) {
                rg[k] = dst[k] >> 8;
                rk[k] = atomicAdd(&cnt[rg[k]], 1);   // LDS atomic: rank in (block,range)
            }
        }
        __syncthreads();
        for (int i = tid; i < NR; i += 512) {
            int c = cnt[i];
            gbase[i] = c ? atomicAdd(&rangeCursor[i], c) : 0;
        }
        __syncthreads();
        if (valid) {
#pragma unroll
            for (int k = 0; k < 8; k++) {
                int pos = gbase[rg[k]] + rk[k];
                if (pos < SEGCAP)   // safety clamp (uniform input: never triggers)
                    gseg[(size_t)rg[k] * SEGCAP + pos] =
                        ((unsigned)(dst[k] & 255) << 17) | (unsigned)src[k];
            }
        }
        return;
    }

    // ---- gemm part ----
    const int lane = tid & 63;
    const int w    = tid >> 6;
    const int head = __builtin_amdgcn_readfirstlane(w >> 1);
    const int ch   = __builtin_amdgcn_readfirstlane(w & 1);
    const int base = (blockIdx.x - BIN_BLOCKS) * GBLK;
    const int node = base + lane;

    const float* __restrict__ wh = W1 + head * 32 + ch * 16;

    float acc[16];
#pragma unroll
    for (int j = 0; j < 16; j++) acc[j] = 0.f;

    for (int kt = 0; kt < 4; kt++) {
        __syncthreads();
        {
            int row = tid >> 3, c4 = tid & 7;
            int n2 = base + row;
            float4 v = make_float4(0.f, 0.f, 0.f, 0.f);
            if (n2 < N_NODES)
                v = *(const float4*)(x + (size_t)n2 * 128 + kt * 32 + c4 * 4);
            xs[(c4 * 4 + 0) * 65 + row] = v.x;
            xs[(c4 * 4 + 1) * 65 + row] = v.y;
            xs[(c4 * 4 + 2) * 65 + row] = v.z;
            xs[(c4 * 4 + 3) * 65 + row] = v.w;
        }
        __syncthreads();

#pragma unroll 4
        for (int kk = 0; kk < 32; kk++) {
            float xv = xs[kk * 65 + lane];
            const float* __restrict__ wr = wh + (size_t)(kt * 32 + kk) * 128;
#pragma unroll
            for (int j = 0; j < 16; j++)
                acc[j] += xv * wr[j];
        }
    }

    if (node < N_NODES) {
        __half2 hp[8];
#pragma unroll
        for (int j = 0; j < 8; j++)
            hp[j] = __floats2half2_rn(acc[2 * j], acc[2 * j + 1]);
        float4* dst = (float4*)(h1 + (size_t)node * 128 + head * 32 + ch * 16);
        dst[0] = ((float4*)hp)[0];
        dst[1] = ((float4*)hp)[1];
    }

    float sa = 0.f, da = 0.f;
#pragma unroll
    for (int j = 0; j < 16; j++) {
        float v = acc[j];
        sa += v * asrc1[head * 32 + ch * 16 + j];
        da += v * adst1[head * 32 + ch * 16 + j];
    }
    sredA[w * 64 + lane] = sa;
    sredB[w * 64 + lane] = da;
    __syncthreads();
    if (tid < 256) {
        int hh = tid >> 6;
        int nd = base + lane;
        if (nd < N_NODES) {
            as1[nd * 4 + hh] = sredA[(hh * 2) * 64 + lane] + sredA[(hh * 2 + 1) * 64 + lane];
            ad1[nd * 4 + hh] = sredB[(hh * 2) * 64 + lane] + sredB[(hh * 2 + 1) * 64 + lane];
        }
    }
}

// =========== finalize: one block per range -> offs + dense bucket ===========
// Reads the range's segment (dense), LDS count+scan for its 256 nodes, places
// srcs into an LDS image of the range's bucket region, streams it out DENSE.
__global__ __launch_bounds__(512) void finalize_kernel(const int* __restrict__ rangeCursor,
                                                       const unsigned* __restrict__ gseg,
                                                       int* __restrict__ offs,
                                                       int* __restrict__ bucket) {
    __shared__ int rsc[256];
    __shared__ int cnt[256];
    __shared__ int csc[256];
    __shared__ int cur[256];
    __shared__ int lbuf[SEGCAP];

    const int tid = threadIdx.x;
    const int r = blockIdx.x;

    // prefix over range sizes (every block computes; 196 ints)
    if (tid < 256) rsc[tid] = (tid < NR) ? min(rangeCursor[tid], SEGCAP) : 0;
    __syncthreads();
    for (int d = 1; d < 256; d <<= 1) {
        int u = (tid < 256 && tid >= d) ? rsc[tid - d] : 0;
        __syncthreads();
        if (tid < 256) rsc[tid] += u;
        __syncthreads();
    }
    const int n = min(rangeCursor[r], SEGCAP);
    const int rbase = rsc[r] - n;
    const unsigned* __restrict__ seg = gseg + (size_t)r * SEGCAP;

    if (tid < 256) cnt[tid] = 0;
    __syncthreads();
    for (int i = tid; i < n; i += 512)
        atomicAdd(&cnt[seg[i] >> 17], 1);
    __syncthreads();
    if (tid < 256) csc[tid] = cnt[tid];
    __syncthreads();
    for (int d = 1; d < 256; d <<= 1) {
        int u = (tid < 256 && tid >= d) ? csc[tid - d] : 0;
        __syncthreads();
        if (tid < 256) csc[tid] += u;
        __syncthreads();
    }
    if (tid < 256) {
        int lofs = csc[tid] - cnt[tid];      // exclusive
        cur[tid] = lofs;
        int node = r * 256 + tid;
        if (node < N_NODES) offs[node] = rbase + lofs;
    }
    if (r == NR - 1 && tid == 0) offs[N_NODES] = rbase + n;
    __syncthreads();
    for (int i = tid; i < n; i += 512) {
        unsigned en = seg[i];
        int p = atomicAdd(&cur[en >> 17], 1);
        lbuf[p] = (int)(en & 0x1FFFFu);
    }
    __syncthreads();
    for (int i = tid; i < n; i += 512)
        bucket[rbase + i] = lbuf[i];
}

// ---------------- layer 1 aggregation (+bias, ELU, layer-2 projection) --------
// wave per node. lane = (edge-subset l>>4, channel-group l&15 -> 8 channels).
__global__ __launch_bounds__(256) void agg1_kernel(const __half* __restrict__ h1,
                                                   const float* __restrict__ as1,
                                                   const float* __restrict__ ad1,
                                                   const int* __restrict__ offs,
                                                   const int* __restrict__ bucket,
                                                   const float* __restrict__ b1,
                                                   const float* __restrict__ W2,
                                                   float* __restrict__ h2s) {
    int w = threadIdx.x >> 6, l = threadIdx.x & 63;
    int node = blockIdx.x * 4 + w;
    if (node >= N_NODES) return;
    int sub = l & 15;
    int ep  = l >> 4;
    int head = sub >> 2;
    float adh = ad1[node * 4 + head];
    int a = offs[node];
    int deg = offs[node + 1] - a;

    float c[8];
#pragma unroll
    for (int k = 0; k < 8; k++) c[k] = 0.f;
    float sx = 0.f;

    for (int i = 0; i < deg; i += 4) {
        int idx = i + ep;
        bool valid = idx < deg;
        int s = bucket[a + (valid ? idx : 0)];
        float e = as1[s * 4 + head] + adh;
        e = fmaxf(e, 0.2f * e);
        float ex = valid ? __expf(e) : 0.f;
        float4 hv = *(const float4*)(h1 + (size_t)s * 128 + sub * 8);
        const __half2* hh = (const __half2*)&hv;
        float2 f0 = __half22float2(hh[0]);
        float2 f1 = __half22float2(hh[1]);
        float2 f2 = __half22float2(hh[2]);
        float2 f3 = __half22float2(hh[3]);
        sx += ex;
        c[0] += ex * f0.x; c[1] += ex * f0.y;
        c[2] += ex * f1.x; c[3] += ex * f1.y;
        c[4] += ex * f2.x; c[5] += ex * f2.y;
        c[6] += ex * f3.x; c[7] += ex * f3.y;
    }

#pragma unroll
    for (int k = 0; k < 8; k++) {
        c[k] += __shfl_xor(c[k], 16, 64);
        c[k] += __shfl_xor(c[k], 32, 64);
    }
    sx += __shfl_xor(sx, 16, 64);
    sx += __shfl_xor(sx, 32, 64);

    float r = 1.f / (sx + 1e-16f);
    float4 blo = ((const float4*)b1)[sub * 2];
    float4 bhi = ((const float4*)b1)[sub * 2 + 1];
    float4 wlo = ((const float4*)W2)[sub * 2];
    float4 whi = ((const float4*)W2)[sub * 2 + 1];
    float ob[8] = {blo.x, blo.y, blo.z, blo.w, bhi.x, bhi.y, bhi.z, bhi.w};
    float ow[8] = {wlo.x, wlo.y, wlo.z, wlo.w, whi.x, whi.y, whi.z, whi.w};
    float p = 0.f;
#pragma unroll
    for (int k = 0; k < 8; k++) {
        float o = c[k] * r + ob[k];
        float el = (o > 0.f) ? o : (__expf(o) - 1.f);
        p += el * ow[k];
    }
    p += __shfl_xor(p, 1, 64);
    p += __shfl_xor(p, 2, 64);
    p += __shfl_xor(p, 4, 64);
    p += __shfl_xor(p, 8, 64);
    if (l == 0) h2s[node] = p;
}

// ---------------- layer 2 aggregation ----------------
__global__ __launch_bounds__(256) void agg2_kernel(const float* __restrict__ h2s,
                                                   const int* __restrict__ offs,
                                                   const int* __restrict__ bucket,
                                                   const float* __restrict__ asrc2,
                                                   const float* __restrict__ adst2,
                                                   const float* __restrict__ b2,
                                                   float* __restrict__ out) {
    int w = threadIdx.x >> 6, l = threadIdx.x & 63;
    int node = blockIdx.x * 4 + w;
    if (node >= N_NODES) return;
    float asc = asrc2[0], adc = adst2[0], bias = b2[0];
    float adn = h2s[node] * adc;
    int a = offs[node], b = offs[node + 1];
    float sx = 0.f, sw = 0.f;
    for (int i = a + l; i < b; i += 64) {
        float hs = h2s[bucket[i]];
        float e = hs * asc + adn;
        e = fmaxf(e, 0.2f * e);
        float ex = __expf(e);
        sx += ex;
        sw += ex * hs;
    }
#pragma unroll
    for (int o = 32; o > 0; o >>= 1) {
        sx += __shfl_xor(sx, o, 64);
        sw += __shfl_xor(sw, o, 64);
    }
    if (l == 0) out[node] = sw / (sx + 1e-16f) + bias;
}

// ---------------- launch ----------------

extern "C" void kernel_launch(void* const* d_in, const int* in_sizes, int n_in,
                              void* d_out, int out_size, void* d_ws, size_t ws_size,
                              hipStream_t stream) {
    const float* x     = (const float*)d_in[0];
    const int*   ei    = (const int*)d_in[1];
    const float* W1    = (const float*)d_in[2];
    const float* asrc1 = (const float*)d_in[3];
    const float* adst1 = (const float*)d_in[4];
    const float* b1    = (const float*)d_in[5];
    const float* W2    = (const float*)d_in[6];
    const float* asrc2 = (const float*)d_in[7];
    const float* adst2 = (const float*)d_in[8];
    const float* b2    = (const float*)d_in[9];
    float* out = (float*)d_out;

    char* ws = (char*)d_ws;
    size_t o = 0;
    auto alloc = [&](size_t bytes) -> void* {
        void* p = ws + o;
        o += (bytes + 255) & ~(size_t)255;
        return p;
    };
    int* offs    = (int*)alloc((size_t)(N_NODES + 1) * 4);
    int* bucket  = (int*)alloc((size_t)E_TOT * 4);
    __half* h1   = (__half*)alloc((size_t)N_NODES * 128 * 2);
    float* as1   = (float*)alloc((size_t)N_NODES * 4 * 4);
    float* ad1   = (float*)alloc((size_t)N_NODES * 4 * 4);
    float* h2s   = (float*)alloc((size_t)N_NODES * 4);
    int* rangeCursor = (int*)alloc((size_t)NR * 4);
    unsigned* gseg   = (unsigned*)alloc((size_t)NR * SEGCAP * 4);

    hipMemsetAsync(rangeCursor, 0, (size_t)NR * 4, stream);

    fat_kernel<<<BIN_BLOCKS + GEMM_BLOCKS, 512, 0, stream>>>(
        x, W1, asrc1, adst1, h1, as1, ad1, ei, rangeCursor, gseg);

    finalize_kernel<<<NR, 512, 0, stream>>>(rangeCursor, gseg, offs, bucket);

    agg1_kernel<<<(N_NODES + 3) / 4, 256, 0, stream>>>(
        h1, as1, ad1, offs, bucket, b1, W2, h2s);

    agg2_kernel<<<(N_NODES + 3) / 4, 256, 0, stream>>>(
        h2s, offs, bucket, asrc2, adst2, b2, out);
}